// Round 1
// 759.468 us; speedup vs baseline: 1.0018x; 1.0018x over previous
//
#include <hip/hip_runtime.h>
#include <hip/hip_bf16.h>
#include <stdint.h>

typedef __hip_bfloat16 bf16;
typedef __attribute__((ext_vector_type(8))) short frag8;     // 8 bf16 = 4 VGPRs
typedef __attribute__((ext_vector_type(4))) float floatx4;   // MFMA acc

#define B_WIN 512
#define L_TOK 196
#define C_DIM 384
#define NH    12
#define HD    32
#define QP    208   // 13*16 q-rows padded
#define KPAD  224   // 14*16 k padded (exactly 56 P-vals/lane = 7 PV chunks)
#define KSTR  40    // kL row stride (80B: 16B-aligned rows, bank stride 20 -> 2-way max)
#define VSTR  232   // vT row stride (464B: 16B-aligned rows, bank stride 20 -> 2-way max)
#define QSCALE 0.17677669529663687f

__device__ __forceinline__ void async_cp16(const void* g, void* l) {
  __builtin_amdgcn_global_load_lds(
      (const __attribute__((address_space(1))) unsigned int*)g,
      (__attribute__((address_space(3))) unsigned int*)l, 16, 0, 0);
}

__device__ __forceinline__ unsigned short f2bf_bits(float f) {
  bf16 b = __float2bfloat16(f);
  return *(unsigned short*)&b;
}

// ---------------- x cast: fp32 -> bf16, 4 elems/thread ----------------
__global__ void cast_to_bf16(const float* __restrict__ src, bf16* __restrict__ dst) {
  int i = blockIdx.x * 256 + threadIdx.x;   // grid sized exactly: n/4 threads
  float4 v = ((const float4*)src)[i];
  ushort4 o;
  o.x = f2bf_bits(v.x); o.y = f2bf_bits(v.y);
  o.z = f2bf_bits(v.z); o.w = f2bf_bits(v.w);
  ((ushort4*)dst)[i] = o;
}

// ---------------- weight transpose+cast: src[K][N] fp32 -> dst[N][K] bf16 ----
__global__ void transpose_cast(const float* __restrict__ src, bf16* __restrict__ dst,
                               int K, int N) {
  int idx = blockIdx.x * 256 + threadIdx.x;
  if (idx >= K * N) return;
  int k = idx / N, n = idx - k * N;
  dst[n * K + k] = __float2bfloat16(src[idx]);
}

// ------- bias precompute: biasf[h][q 208][j 224] fp32, k = pi(j) permuted ----
// pi(j): t=j>>4, qd=(j>>2)&3, r=j&3 -> k = (t>>1)*32 + qd*8 + (t&1)*4 + r
// (bijection on [0,224); makes the swapped-QK P registers land exactly in
//  PV A-fragment order -> P never leaves registers)
// k >= 196: -1e30 (exp -> 0 == mask). q >= 196: 0 (rows discarded at store).
__global__ void bias_fill(const float* __restrict__ table, const int* __restrict__ rel,
                          float* __restrict__ biasf) {
  int idx = blockIdx.x * 256 + threadIdx.x;  // 12*208*224 = 559104 exact
  int h = idx / (QP * KPAD);
  int rem = idx - h * (QP * KPAD);
  int q = rem / KPAD, j = rem - q * KPAD;
  int t = j >> 4, qd = (j >> 2) & 3, rr = j & 3;
  int k = (t >> 1) * 32 + qd * 8 + (t & 1) * 4 + rr;
  float v;
  if (q >= L_TOK)      v = 0.f;
  else if (k >= L_TOK) v = -1e30f;
  else                 v = table[rel[q * L_TOK + k] * NH + h];
  biasf[idx] = v;
}

__device__ __forceinline__ void storev(bf16* p, float v)  { *p = __float2bfloat16(v); }
__device__ __forceinline__ void storev(float* p, float v) { *p = v; }

// ------- GEMM: C[M,N] = A[M,K](lda) @ Bt[N,K]^T + bias, C row-stride = N -------
// cols < qcols get *= QSCALE in the epilogue (folds attention scale into Q)
// 2-phase double-buffered: next tile's global_load_lds issued BEFORE current
// tile's ds_read+MFMA; single __syncthreads per k-step drains it afterwards.
template <typename OT>
__global__ __launch_bounds__(256) void gemm_bt(
    const bf16* __restrict__ A, const bf16* __restrict__ Bt,
    const float* __restrict__ bias, OT* __restrict__ C,
    int M, int N, int K, int lda, int qcols) {
  __shared__ __align__(16) bf16 sA[2][128 * 32];
  __shared__ __align__(16) bf16 sB[2][128 * 32];
  const int tid = threadIdx.x;
  const int wave = tid >> 6, lane = tid & 63;
  const long bm = (long)blockIdx.x * 128;
  const long bn = (long)blockIdx.y * 128;

  const int srow = wave * 32 + (lane >> 2);
  const int scol = (lane & 3) * 8;
  const bf16* gA = A + (bm + srow) * (long)lda + scol;
  const bf16* gB = Bt + (bn + srow) * (long)K + scol;

  floatx4 acc[4][4];
#pragma unroll
  for (int i = 0; i < 4; i++)
#pragma unroll
    for (int j = 0; j < 4; j++) acc[i][j] = (floatx4)(0.f);

  const int wr = (wave & 1) * 64;
  const int wc = (wave >> 1) * 64;

  // prologue: stage tile 0 into buffer 0
#pragma unroll
  for (int j = 0; j < 2; j++) {
    async_cp16(gA + (size_t)j * 16 * lda, &sA[0][(wave * 32 + j * 16) * 32]);
    async_cp16(gB + (size_t)j * 16 * K, &sB[0][(wave * 32 + j * 16) * 32]);
  }
  __syncthreads();

  int cur = 0;
  for (int k0 = 0; k0 < K; k0 += 32) {
    if (k0 + 32 < K) {  // issue next tile early; latency hides under MFMAs
#pragma unroll
      for (int j = 0; j < 2; j++) {
        async_cp16(gA + (size_t)j * 16 * lda + (k0 + 32),
                   &sA[cur ^ 1][(wave * 32 + j * 16) * 32]);
        async_cp16(gB + (size_t)j * 16 * K + (k0 + 32),
                   &sB[cur ^ 1][(wave * 32 + j * 16) * 32]);
      }
    }
    frag8 af[4], bfr[4];
#pragma unroll
    for (int mi = 0; mi < 4; mi++)
      af[mi] = *(const frag8*)&sA[cur][(wr + mi * 16 + (lane & 15)) * 32 + (lane >> 4) * 8];
#pragma unroll
    for (int ni = 0; ni < 4; ni++)
      bfr[ni] = *(const frag8*)&sB[cur][(wc + ni * 16 + (lane & 15)) * 32 + (lane >> 4) * 8];
#pragma unroll
    for (int mi = 0; mi < 4; mi++)
#pragma unroll
      for (int ni = 0; ni < 4; ni++)
        acc[mi][ni] = __builtin_amdgcn_mfma_f32_16x16x32_bf16(af[mi], bfr[ni], acc[mi][ni], 0, 0, 0);
    __syncthreads();   // drains prefetch (vmcnt) + this tile's ds_reads (lgkm)
    cur ^= 1;
  }

#pragma unroll
  for (int ni = 0; ni < 4; ni++) {
    const long col = bn + wc + ni * 16 + (lane & 15);
    const float bv = bias[col];
#pragma unroll
    for (int mi = 0; mi < 4; mi++)
#pragma unroll
      for (int r = 0; r < 4; r++) {
        const long row = bm + wr + mi * 16 + (lane >> 4) * 4 + r;
        float val = acc[mi][ni][r] + bv;
        if (col < qcols) val *= QSCALE;
        storev(&C[row * N + col], val);
      }
  }
}

// ---------------- fused window attention (v3: register-resident P) ----------
// one block per (b,h); wave owns 16 q-rows per rg.
// QK^T computed SWAPPED: s = mfma(K, Q) so each lane holds one full P row
// (q = row0 + lane&15). K rows and bias cols staged under permutation pi so
// the 56 per-lane P values are exactly the PV A-fragment in order:
//   ap[kk] = { s[2kk][0..3], s[2kk+1][0..3] }  (pure in-register bf16 casts).
// No P LDS buffer -> LDS = 32 KB exactly -> 5 blocks/CU.
__global__ __launch_bounds__(256) void attn_win(
    bf16* __restrict__ qkv, const float* __restrict__ biasf) {
  __shared__ __align__(16) bf16 kL[KPAD * KSTR];   // 17920 B
  __shared__ __align__(16) bf16 vT[HD * VSTR];     // 14848 B  (total 32768 B)
  const int b = blockIdx.x, h = blockIdx.y;
  const int tid = threadIdx.x, wave = tid >> 6, lane = tid & 63;
  bf16* base = qkv + (size_t)b * L_TOK * (3 * C_DIM);

  // stage K permuted: kL row j holds K[pi(j)] (zeros for pi(j) >= 196)
  for (int idx = tid; idx < KPAD * 4; idx += 256) {
    int j = idx >> 2, c8 = (idx & 3) * 8;
    int t = j >> 4, qd = (j >> 2) & 3, rr = j & 3;
    int k = (t >> 1) * 32 + qd * 8 + (t & 1) * 4 + rr;
    uint4 val = make_uint4(0, 0, 0, 0);
    if (k < L_TOK)
      val = *(const uint4*)(base + k * (3 * C_DIM) + C_DIM + h * HD + c8);
    *(uint4*)&kL[j * KSTR + c8] = val;
  }
  // stage V transposed (natural k order): 2 rows/thread, paired u32 writes
  for (int idx = tid; idx < 98 * 4; idx += 256) {
    int r0 = idx >> 2, c8 = (idx & 3) * 8;
    const bf16* g0 = base + (2 * r0) * (3 * C_DIM) + 2 * C_DIM + h * HD + c8;
    uint4 v0 = *(const uint4*)g0;
    uint4 v1 = *(const uint4*)(g0 + 3 * C_DIM);
    ushort e0[8], e1[8];
    *(uint4*)e0 = v0; *(uint4*)e1 = v1;
#pragma unroll
    for (int e = 0; e < 8; e++) {
      uint32_t pack = (uint32_t)e0[e] | ((uint32_t)e1[e] << 16);
      *(uint32_t*)&vT[(c8 + e) * VSTR + 2 * r0] = pack;
    }
  }
  // zero V pad rows [196,224)
  for (int idx = tid; idx < HD * 14; idx += 256) {
    int d = idx / 14, pr = idx - d * 14;
    *(uint32_t*)&vT[d * VSTR + L_TOK + 2 * pr] = 0;
  }
  __syncthreads();

  const int colb = lane & 15;
  const int quad = lane >> 4;
  const int rsub = quad * 4;
  const float* bB = biasf + (size_t)h * QP * KPAD;

  for (int rg = wave; rg < 13; rg += 4) {
    const int row0 = rg * 16;
    // Q as the MFMA B-operand, direct from global (B[n=lane&15=q][d=quad*8+i])
    int qrow = row0 + colb;
    if (qrow > L_TOK - 1) qrow = L_TOK - 1;
    const frag8 aq = *(const frag8*)(base + qrow * (3 * C_DIM) + h * HD + quad * 8);

    // acc init = bias in swapped C-layout: s[t][r] <-> (k-pos t*16+quad*4+r, q=colb)
    floatx4 s[14];
#pragma unroll
    for (int t = 0; t < 14; t++)
      s[t] = *(const floatx4*)(bB + (size_t)(row0 + colb) * KPAD + t * 16 + rsub);

#pragma unroll
    for (int t = 0; t < 14; t++) {
      const frag8 bk = *(const frag8*)&kL[(t * 16 + colb) * KSTR + quad * 8];
      s[t] = __builtin_amdgcn_mfma_f32_16x16x32_bf16(bk, aq, s[t], 0, 0, 0);
    }

    // softmax without max-pass; each lane owns one full P row -> local sum,
    // then reduce across the 4 quads only (lanes +-16, +-32)
    float lsum = 0.f;
#pragma unroll
    for (int t = 0; t < 14; t++)
#pragma unroll
      for (int r = 0; r < 4; r++) {
        float p = __expf(s[t][r]);
        s[t][r] = p;
        lsum += p;
      }
    lsum += __shfl_xor(lsum, 16, 64);
    lsum += __shfl_xor(lsum, 32, 64);
    const float rl = 1.0f / lsum;

    // O[16][32] = P[16][224] @ V[224][32]; A-frag built in-register
    floatx4 o[2] = {(floatx4)(0.f), (floatx4)(0.f)};
#pragma unroll
    for (int kk = 0; kk < 7; kk++) {
      frag8 ap;
#pragma unroll
      for (int e = 0; e < 4; e++) ap[e] = (short)f2bf_bits(s[2 * kk][e]);
#pragma unroll
      for (int e = 0; e < 4; e++) ap[4 + e] = (short)f2bf_bits(s[2 * kk + 1][e]);
#pragma unroll
      for (int nt = 0; nt < 2; nt++) {
        const frag8 bv = *(const frag8*)&vT[(nt * 16 + colb) * VSTR + kk * 32 + quad * 8];
        o[nt] = __builtin_amdgcn_mfma_f32_16x16x32_bf16(ap, bv, o[nt], 0, 0, 0);
      }
    }
    // normalize: O rows are q = row0 + rsub + r; fetch that row's 1/l from quad0
    float rln[4];
#pragma unroll
    for (int r = 0; r < 4; r++) rln[r] = __shfl(rl, rsub + r, 64);
#pragma unroll
    for (int nt = 0; nt < 2; nt++)
#pragma unroll
      for (int r = 0; r < 4; r++) {
        const int grow = row0 + rsub + r;
        if (grow < L_TOK)
          base[(size_t)grow * (3 * C_DIM) + h * HD + nt * 16 + colb] =
              __float2bfloat16(o[nt][r] * rln[r]);
      }
  }
}

extern "C" void kernel_launch(void* const* d_in, const int* in_sizes, int n_in,
                              void* d_out, int out_size, void* d_ws, size_t ws_size,
                              hipStream_t stream) {
  const float* x      = (const float*)d_in[0];
  const float* qkv_w  = (const float*)d_in[1];
  const float* qkv_b  = (const float*)d_in[2];
  const float* proj_w = (const float*)d_in[3];
  const float* proj_b = (const float*)d_in[4];
  const float* btab   = (const float*)d_in[5];
  const int*   relidx = (const int*)d_in[6];
  float* out = (float*)d_out;

  const size_t M = (size_t)B_WIN * L_TOK;  // 100352
  char* ws = (char*)d_ws;
  size_t off = 0;
  bf16*  qkv   = (bf16*)(ws + off);  off += M * 1152 * 2;              // 231.2 MB
  bf16*  wT1   = (bf16*)(ws + off);  off += (size_t)1152 * 384 * 2;    // 0.88 MB
  bf16*  wT2   = (bf16*)(ws + off);  off += (size_t)384 * 384 * 2;     // 0.29 MB
  float* biasf = (float*)(ws + off); off += (size_t)NH * QP * KPAD * 4;// 2.24 MB
  // total 234.6 MB

  // x cast to bf16, scratch-aliased into d_out (gemm3 fully overwrites later)
  bf16* xb = (bf16*)d_out;

  cast_to_bf16<<<(int)(M * C_DIM / 4 / 256), 256, 0, stream>>>(x, xb);
  transpose_cast<<<(384 * 1152 + 255) / 256, 256, 0, stream>>>(qkv_w, wT1, 384, 1152);
  transpose_cast<<<(384 * 384 + 255) / 256, 256, 0, stream>>>(proj_w, wT2, 384, 384);
  bias_fill<<<(NH * QP * KPAD) / 256, 256, 0, stream>>>(btab, relidx, biasf);

  gemm_bt<bf16><<<dim3(784, 9), 256, 0, stream>>>(xb, wT1, qkv_b, qkv,
                                                  (int)M, 1152, 384, 384, C_DIM);
  attn_win<<<dim3(B_WIN, NH), 256, 0, stream>>>(qkv, biasf);
  gemm_bt<float><<<dim3(784, 3), 256, 0, stream>>>(qkv, wT2, proj_b, out,
                                                   (int)M, 384, 384, 1152, 0);
}

// Round 2
// 637.576 us; speedup vs baseline: 1.1933x; 1.1912x over previous
//
#include <hip/hip_runtime.h>
#include <hip/hip_bf16.h>
#include <stdint.h>

typedef __hip_bfloat16 bf16;
typedef __attribute__((ext_vector_type(8))) short frag8;     // 8 bf16 = 4 VGPRs
typedef __attribute__((ext_vector_type(4))) float floatx4;   // MFMA acc

#define B_WIN 512
#define L_TOK 196
#define C_DIM 384
#define NH    12
#define HD    32
#define QP    208   // 13*16 q-rows padded
#define KPAD  224   // 14*16 k padded (exactly 56 P-vals/lane = 7 PV chunks)
#define VSTR  232   // vT row stride (464B: 16B-aligned rows, bank stride 20 -> 2-way max)
// scale = hd^-0.5 * log2(e)  (exp2 softmax; base change folded into logits+bias)
#define QSCALE 0.2550348555f

#if defined(__has_builtin)
#if __has_builtin(__builtin_amdgcn_exp2f)
#define EXP2(x) __builtin_amdgcn_exp2f(x)
#endif
#endif
#ifndef EXP2
#define EXP2(x) exp2f(x)
#endif

__device__ __forceinline__ void async_cp16(const void* g, void* l) {
  __builtin_amdgcn_global_load_lds(
      (const __attribute__((address_space(1))) unsigned int*)g,
      (__attribute__((address_space(3))) unsigned int*)l, 16, 0, 0);
}

__device__ __forceinline__ unsigned short f2bf_bits(float f) {
  bf16 b = __float2bfloat16(f);
  return *(unsigned short*)&b;
}

// ---------------- x cast: fp32 -> bf16, 4 elems/thread ----------------
__global__ void cast_to_bf16(const float* __restrict__ src, bf16* __restrict__ dst) {
  int i = blockIdx.x * 256 + threadIdx.x;   // grid sized exactly: n/4 threads
  float4 v = ((const float4*)src)[i];
  ushort4 o;
  o.x = f2bf_bits(v.x); o.y = f2bf_bits(v.y);
  o.z = f2bf_bits(v.z); o.w = f2bf_bits(v.w);
  ((ushort4*)dst)[i] = o;
}

// ---------------- weight transpose+cast: src[K][N] fp32 -> dst[N][K] bf16 ----
__global__ void transpose_cast(const float* __restrict__ src, bf16* __restrict__ dst,
                               int K, int N) {
  int idx = blockIdx.x * 256 + threadIdx.x;
  if (idx >= K * N) return;
  int k = idx / N, n = idx - k * N;
  dst[n * K + k] = __float2bfloat16(src[idx]);
}

// ------- bias precompute: biasf[h][q 208][j 224] fp32, k = pi(j) permuted ----
// pi(j): t=j>>4, qd=(j>>2)&3, r=j&3 -> k = (t>>1)*32 + qd*8 + (t&1)*4 + r
// Values pre-multiplied by log2(e) (exp2 softmax). k >= 196: -1e30 (exp2 -> 0
// masks those columns REGARDLESS of K content -> K pad rows need no zeroing).
__global__ void bias_fill(const float* __restrict__ table, const int* __restrict__ rel,
                          float* __restrict__ biasf) {
  int idx = blockIdx.x * 256 + threadIdx.x;  // 12*208*224 = 559104 exact
  int h = idx / (QP * KPAD);
  int rem = idx - h * (QP * KPAD);
  int q = rem / KPAD, j = rem - q * KPAD;
  int t = j >> 4, qd = (j >> 2) & 3, rr = j & 3;
  int k = (t >> 1) * 32 + qd * 8 + (t & 1) * 4 + rr;
  float v;
  if (q >= L_TOK)      v = 0.f;
  else if (k >= L_TOK) v = -1e30f;
  else                 v = table[rel[q * L_TOK + k] * NH + h] * 1.4426950408889634f;
  biasf[idx] = v;
}

__device__ __forceinline__ void storev(bf16* p, float v)  { *p = __float2bfloat16(v); }
__device__ __forceinline__ void storev(float* p, float v) { *p = v; }

// ------- GEMM: C[M,N] = A[M,K](lda) @ Bt[N,K]^T + bias, C row-stride = N -------
// 1-D grid with M-panel swizzle: PANEL consecutive bm-tiles x all bn-tiles per
// super-block -> A panel (5.5 MB) stays L2/L3-hot across the nbn re-reads.
// cols < qcols get *= QSCALE in the epilogue (folds attention scale into Q).
template <typename OT>
__global__ __launch_bounds__(256) void gemm_bt(
    const bf16* __restrict__ A, const bf16* __restrict__ Bt,
    const float* __restrict__ bias, OT* __restrict__ C,
    int M, int N, int K, int lda, int qcols, int nbn, int panel) {
  __shared__ __align__(16) bf16 sA[2][128 * 32];
  __shared__ __align__(16) bf16 sB[2][128 * 32];
  const int tid = threadIdx.x;
  const int wave = tid >> 6, lane = tid & 63;
  const int SUPER = panel * nbn;
  const int bid = blockIdx.x;
  const int sb = bid / SUPER, rsp = bid - sb * SUPER;
  const long bm = (long)(sb * panel + rsp % panel) * 128;
  const long bn = (long)(rsp / panel) * 128;

  const int srow = wave * 32 + (lane >> 2);
  const int scol = (lane & 3) * 8;
  const bf16* gA = A + (bm + srow) * (long)lda + scol;
  const bf16* gB = Bt + (bn + srow) * (long)K + scol;

  floatx4 acc[4][4];
#pragma unroll
  for (int i = 0; i < 4; i++)
#pragma unroll
    for (int j = 0; j < 4; j++) acc[i][j] = (floatx4)(0.f);

  const int wr = (wave & 1) * 64;
  const int wc = (wave >> 1) * 64;

  // prologue: stage tile 0 into buffer 0
#pragma unroll
  for (int j = 0; j < 2; j++) {
    async_cp16(gA + (size_t)j * 16 * lda, &sA[0][(wave * 32 + j * 16) * 32]);
    async_cp16(gB + (size_t)j * 16 * K, &sB[0][(wave * 32 + j * 16) * 32]);
  }
  __syncthreads();

  int cur = 0;
  for (int k0 = 0; k0 < K; k0 += 32) {
    if (k0 + 32 < K) {  // issue next tile early; latency hides under MFMAs
#pragma unroll
      for (int j = 0; j < 2; j++) {
        async_cp16(gA + (size_t)j * 16 * lda + (k0 + 32),
                   &sA[cur ^ 1][(wave * 32 + j * 16) * 32]);
        async_cp16(gB + (size_t)j * 16 * K + (k0 + 32),
                   &sB[cur ^ 1][(wave * 32 + j * 16) * 32]);
      }
    }
    frag8 af[4], bfr[4];
#pragma unroll
    for (int mi = 0; mi < 4; mi++)
      af[mi] = *(const frag8*)&sA[cur][(wr + mi * 16 + (lane & 15)) * 32 + (lane >> 4) * 8];
#pragma unroll
    for (int ni = 0; ni < 4; ni++)
      bfr[ni] = *(const frag8*)&sB[cur][(wc + ni * 16 + (lane & 15)) * 32 + (lane >> 4) * 8];
#pragma unroll
    for (int mi = 0; mi < 4; mi++)
#pragma unroll
      for (int ni = 0; ni < 4; ni++)
        acc[mi][ni] = __builtin_amdgcn_mfma_f32_16x16x32_bf16(af[mi], bfr[ni], acc[mi][ni], 0, 0, 0);
    __syncthreads();   // drains prefetch (vmcnt) + this tile's ds_reads (lgkm)
    cur ^= 1;
  }

#pragma unroll
  for (int ni = 0; ni < 4; ni++) {
    const long col = bn + wc + ni * 16 + (lane & 15);
    const float bv = bias[col];
#pragma unroll
    for (int mi = 0; mi < 4; mi++)
#pragma unroll
      for (int r = 0; r < 4; r++) {
        const long row = bm + wr + mi * 16 + (lane >> 4) * 4 + r;
        float val = acc[mi][ni][r] + bv;
        if (col < qcols) val *= QSCALE;
        storev(&C[row * N + col], val);
      }
  }
}

// ---------------- fused window attention (v4: latency-hidden) ----------------
// v3 structure (register-resident P via permuted-K swapped QK^T) + MLP fixes:
//  - K staged via global_load_lds (async, linear 64B rows, slot-XOR swizzle
//    applied on the per-lane GLOBAL source; read back with the same XOR ->
//    2-way banks). Pad rows clamped, masked by the -1e30 bias (exp2 -> 0).
//  - V gather loads batched (issued first), unpack/ds_write after.
//  - Q frags for all rg prefetched pre-barrier; first bias tile pre-barrier;
//    subsequent bias tiles loaded inside the PV loop as s[] pairs die.
__global__ __launch_bounds__(256, 4) void attn_win(
    bf16* __restrict__ qkv, const float* __restrict__ biasf) {
  __shared__ __align__(16) bf16 kL[KPAD * 32];     // 14336 B, linear 64B rows
  __shared__ __align__(16) bf16 vT[HD * VSTR];     // 14848 B  (total 29184 B)
  const int b = blockIdx.x, h = blockIdx.y;
  const int tid = threadIdx.x, wave = tid >> 6, lane = tid & 63;
  bf16* base = qkv + (size_t)b * L_TOK * (3 * C_DIM);

  const int colb = lane & 15;
  const int quad = lane >> 4;
  const int rsub = quad * 4;
  const int kswz = (quad ^ ((colb >> 1) & 3)) * 8;   // slot-XOR for kL reads

  // ---- V gather: issue ALL global loads first (oldest in vmem queue) ----
  const bf16* vbase = base + 2 * C_DIM + h * HD;
  const int i0 = tid;                       // task < 392 always
  const int r0a = i0 >> 2, c8a = (i0 & 3) * 8;
  const bf16* ga = vbase + (size_t)(2 * r0a) * (3 * C_DIM) + c8a;
  uint4 a0 = *(const uint4*)ga;
  uint4 a1 = *(const uint4*)(ga + 3 * C_DIM);
  const int i1 = tid + 256;
  const bool h1 = i1 < 392;
  const int r0b = h1 ? (i1 >> 2) : r0a, c8b = h1 ? (i1 & 3) * 8 : c8a;
  const bf16* gb = vbase + (size_t)(2 * r0b) * (3 * C_DIM) + c8b;
  uint4 b0 = make_uint4(0, 0, 0, 0), b1 = make_uint4(0, 0, 0, 0);
  if (h1) { b0 = *(const uint4*)gb; b1 = *(const uint4*)(gb + 3 * C_DIM); }

  // ---- K: async global->LDS, 14 chunks of 1024B (rows j = c*16..c*16+15).
  // LDS is linear; the slot permutation is applied on the global source:
  // LDS slot w of row j holds K[pi(j)] quad (w ^ ((j>>1)&3)).
  for (int c = wave; c < 14; c += 4) {
    const int j = c * 16 + (lane >> 2);
    const int slot = lane & 3;
    const int t = j >> 4, qd = (j >> 2) & 3, rr = j & 3;
    int k = (t >> 1) * 32 + qd * 8 + (t & 1) * 4 + rr;
    if (k > L_TOK - 1) k = L_TOK - 1;       // clamp: bias -1e30 masks these cols
    const int sj = (j >> 1) & 3;
    const bf16* src = base + (size_t)k * (3 * C_DIM) + C_DIM + h * HD + ((slot ^ sj) * 8);
    async_cp16(src, &kL[c * 512]);
  }

  // ---- Q prefetch for all rg iterations (latency hides under staging) ----
  frag8 aqv[4];
#pragma unroll
  for (int i = 0; i < 4; i++) {
    int rg = wave + 4 * i; if (rg > 12) rg = 12;
    int qrow = rg * 16 + colb; if (qrow > L_TOK - 1) qrow = L_TOK - 1;
    aqv[i] = *(const frag8*)(base + (size_t)qrow * (3 * C_DIM) + h * HD + quad * 8);
  }

  // ---- first-rg bias prefetch (s is the MFMA C-init) ----
  const float* bB = biasf + (size_t)h * QP * KPAD;
  floatx4 s[14];
#pragma unroll
  for (int t = 0; t < 14; t++)
    s[t] = *(const floatx4*)(bB + (size_t)(wave * 16 + colb) * KPAD + t * 16 + rsub);

  // ---- V transpose writes (vmcnt wait covers only the V loads) ----
  {
    ushort ea0[8], ea1[8];
    *(uint4*)ea0 = a0; *(uint4*)ea1 = a1;
#pragma unroll
    for (int e = 0; e < 8; e++) {
      uint32_t pack = (uint32_t)ea0[e] | ((uint32_t)ea1[e] << 16);
      *(uint32_t*)&vT[(c8a + e) * VSTR + 2 * r0a] = pack;
    }
    if (h1) {
      ushort eb0[8], eb1[8];
      *(uint4*)eb0 = b0; *(uint4*)eb1 = b1;
#pragma unroll
      for (int e = 0; e < 8; e++) {
        uint32_t pack = (uint32_t)eb0[e] | ((uint32_t)eb1[e] << 16);
        *(uint32_t*)&vT[(c8b + e) * VSTR + 2 * r0b] = pack;
      }
    }
  }
  // zero V pad rows [196,224) (P there is exactly 0, but LDS garbage could be NaN)
  for (int idx = tid; idx < HD * 14; idx += 256) {
    int d = idx / 14, pr = idx - d * 14;
    *(uint32_t*)&vT[d * VSTR + L_TOK + 2 * pr] = 0;
  }
  __syncthreads();

#pragma unroll
  for (int ii = 0; ii < 4; ii++) {
    const int rg = wave + 4 * ii;
    if (rg < 13) {
      const int row0 = rg * 16;
      const bool pre = (rg + 4 < 13);

      // QK^T (swapped): s[t] += K_perm-tile(t) . q
#pragma unroll
      for (int t = 0; t < 14; t++) {
        const frag8 bk = *(const frag8*)&kL[(t * 16 + colb) * 32 + kswz];
        s[t] = __builtin_amdgcn_mfma_f32_16x16x32_bf16(bk, aqv[ii], s[t], 0, 0, 0);
      }

      // exp2 + row-sum (lane owns full P row; reduce across 4 quads only)
      float lsum = 0.f;
#pragma unroll
      for (int t = 0; t < 14; t++)
#pragma unroll
        for (int r = 0; r < 4; r++) {
          float p = EXP2(s[t][r]);
          s[t][r] = p;
          lsum += p;
        }
      lsum += __shfl_xor(lsum, 16, 64);
      lsum += __shfl_xor(lsum, 32, 64);
      const float rl = 1.0f / lsum;
      float rln[4];
#pragma unroll
      for (int r = 0; r < 4; r++) rln[r] = __shfl(rl, rsub + r, 64);

      // O[16][32] = P @ V; ap built in-register; as each s-pair dies,
      // reload it with the NEXT rg's bias (overlaps PV MFMAs, T14-style)
      const float* bBn = bB + (size_t)(row0 + 64 + colb) * KPAD;
      floatx4 o[2] = {(floatx4)(0.f), (floatx4)(0.f)};
#pragma unroll
      for (int kk = 0; kk < 7; kk++) {
        frag8 ap;
#pragma unroll
        for (int e = 0; e < 4; e++) ap[e] = (short)f2bf_bits(s[2 * kk][e]);
#pragma unroll
        for (int e = 0; e < 4; e++) ap[4 + e] = (short)f2bf_bits(s[2 * kk + 1][e]);
        if (pre) {
          s[2 * kk]     = *(const floatx4*)(bBn + (2 * kk) * 16 + rsub);
          s[2 * kk + 1] = *(const floatx4*)(bBn + (2 * kk + 1) * 16 + rsub);
        }
#pragma unroll
        for (int nt = 0; nt < 2; nt++) {
          const frag8 bv = *(const frag8*)&vT[(nt * 16 + colb) * VSTR + kk * 32 + quad * 8];
          o[nt] = __builtin_amdgcn_mfma_f32_16x16x32_bf16(ap, bv, o[nt], 0, 0, 0);
        }
      }
      // normalize + write into the Q-slice (Q already prefetched pre-barrier)
#pragma unroll
      for (int nt = 0; nt < 2; nt++)
#pragma unroll
        for (int r = 0; r < 4; r++) {
          const int grow = row0 + rsub + r;
          if (grow < L_TOK)
            base[(size_t)grow * (3 * C_DIM) + h * HD + nt * 16 + colb] =
                __float2bfloat16(o[nt][r] * rln[r]);
        }
    }
  }
}

extern "C" void kernel_launch(void* const* d_in, const int* in_sizes, int n_in,
                              void* d_out, int out_size, void* d_ws, size_t ws_size,
                              hipStream_t stream) {
  const float* x      = (const float*)d_in[0];
  const float* qkv_w  = (const float*)d_in[1];
  const float* qkv_b  = (const float*)d_in[2];
  const float* proj_w = (const float*)d_in[3];
  const float* proj_b = (const float*)d_in[4];
  const float* btab   = (const float*)d_in[5];
  const int*   relidx = (const int*)d_in[6];
  float* out = (float*)d_out;

  const size_t M = (size_t)B_WIN * L_TOK;  // 100352
  char* ws = (char*)d_ws;
  size_t off = 0;
  bf16*  qkv   = (bf16*)(ws + off);  off += M * 1152 * 2;              // 231.2 MB
  bf16*  wT1   = (bf16*)(ws + off);  off += (size_t)1152 * 384 * 2;    // 0.88 MB
  bf16*  wT2   = (bf16*)(ws + off);  off += (size_t)384 * 384 * 2;     // 0.29 MB
  float* biasf = (float*)(ws + off); off += (size_t)NH * QP * KPAD * 4;// 2.24 MB
  // total 234.6 MB

  // x cast to bf16, scratch-aliased into d_out (gemm3 fully overwrites later)
  bf16* xb = (bf16*)d_out;

  cast_to_bf16<<<(int)(M * C_DIM / 4 / 256), 256, 0, stream>>>(x, xb);
  transpose_cast<<<(384 * 1152 + 255) / 256, 256, 0, stream>>>(qkv_w, wT1, 384, 1152);
  transpose_cast<<<(384 * 384 + 255) / 256, 256, 0, stream>>>(proj_w, wT2, 384, 384);
  bias_fill<<<(NH * QP * KPAD) / 256, 256, 0, stream>>>(btab, relidx, biasf);

  // 784 M-tiles; panel 56 (784 = 14*56): A-panel 5.5 MB reused across all bn
  gemm_bt<bf16><<<784 * 9, 256, 0, stream>>>(xb, wT1, qkv_b, qkv,
                                             (int)M, 1152, 384, 384, C_DIM, 9, 56);
  attn_win<<<dim3(B_WIN, NH), 256, 0, stream>>>(qkv, biasf);
  gemm_bt<float><<<784 * 3, 256, 0, stream>>>(qkv, wT2, proj_b, out,
                                              (int)M, 384, 384, 1152, 0, 3, 56);
}